// Round 3
// baseline (40.588 us; speedup 1.0000x reference)
//
#include <hip/hip_runtime.h>

typedef float floatx4 __attribute__((ext_vector_type(4)));

// Problem constants
constexpr int H    = 768;
constexpr int W4   = 1280 / 4;        // float4 per row = 320
constexpr int PAD  = 4;               // shift == one float4 (aligned!)
constexpr int NVEC = 16 * 768 * W4;   // 3,932,160 float4 elements
constexpr int UNROLL = 4;
constexpr int BLOCK  = 256;
constexpr int PER_BLOCK = BLOCK * UNROLL;      // 1024
constexpr int GRID = NVEC / PER_BLOCK;         // 3840 (exact)

__global__ __launch_bounds__(256)
void bilateral_kernel(const floatx4* __restrict__ img,
                      const floatx4* __restrict__ disp,
                      floatx4* __restrict__ out)
{
    const int base = blockIdx.x * PER_BLOCK + threadIdx.x;

    const float DIST = 0.16901332f;   // exp(-16/9), spatial gaussian at (4,4)
    const float EPS  = 1e-12f;

    int     idx[UNROLL];
    floatx4 a[UNROLL], s[UNROLL], d[UNROLL];
    bool    sOK[UNROLL], dOK[UNROLL];

    // Issue all 12 loads with no branches: clamp OOB addresses to a safe
    // in-range address (the center), zero via cndmask afterwards.
#pragma unroll
    for (int k = 0; k < UNROLL; ++k) {
        idx[k] = base + k * BLOCK;
        const int c4 = idx[k] % W4;
        const int r  = (idx[k] / W4) % H;
        sOK[k] = (r + PAD < H) & (c4 + 1 < W4);
        dOK[k] = (r >= PAD) & (c4 >= 1);
        const int sI = sOK[k] ? idx[k] + PAD * W4 + 1 : idx[k];
        const int dI = dOK[k] ? idx[k] - PAD * W4 - 1 : idx[k];
        a[k] = img[idx[k]];
        s[k] = img[sI];
        d[k] = disp[dI];
    }

#pragma unroll
    for (int k = 0; k < UNROLL; ++k) {
        if (!sOK[k]) s[k] = (floatx4)0.0f;
        if (!dOK[k]) d[k] = (floatx4)0.0f;

        floatx4 o;
#pragma unroll
        for (int j = 0; j < 4; ++j) {
            float diff = a[k][j] - s[k][j];
            float w    = DIST * __expf(diff * diff * -0.125f); // exp(-diff²/8)
            // (d*w + eps) / (w + eps) via fast reciprocal (v_rcp_f32, ~1e-7 rel)
            o[j] = __builtin_fmaf(d[k][j], w, EPS) * __builtin_amdgcn_rcpf(w + EPS);
        }

        // Non-temporal: don't let the write stream evict L3-resident inputs.
        __builtin_nontemporal_store(o, &out[idx[k]]);
    }
}

extern "C" void kernel_launch(void* const* d_in, const int* in_sizes, int n_in,
                              void* d_out, int out_size, void* d_ws, size_t ws_size,
                              hipStream_t stream) {
    const floatx4* img  = (const floatx4*)d_in[0];   // leftImage
    const floatx4* disp = (const floatx4*)d_in[1];   // estDisp
    floatx4* out = (floatx4*)d_out;

    bilateral_kernel<<<GRID, BLOCK, 0, stream>>>(img, disp, out);
}

// Round 4
// 32.720 us; speedup vs baseline: 1.2405x; 1.2405x over previous
//
#include <hip/hip_runtime.h>

typedef float floatx4 __attribute__((ext_vector_type(4)));

// Problem constants
constexpr int H    = 768;
constexpr int W4   = 1280 / 4;        // float4 per row = 320
constexpr int PAD  = 4;               // shift == one float4 (aligned!)
constexpr int NVEC = 16 * 768 * W4;   // 3,932,160 float4 elements
constexpr int UNROLL = 4;
constexpr int BLOCK  = 256;
constexpr int PER_BLOCK = BLOCK * UNROLL;      // 1024
constexpr int GRID = NVEC / PER_BLOCK;         // 3840 (exact)
constexpr int NXCD  = 8;
constexpr int CHUNK = GRID / NXCD;             // 480 (GRID % 8 == 0 -> bijective)

__global__ __launch_bounds__(256)
void bilateral_kernel(const floatx4* __restrict__ img,
                      const floatx4* __restrict__ disp,
                      floatx4* __restrict__ out)
{
    // XCD-aware swizzle: HW round-robins consecutive blockIdx across the 8
    // XCDs; remap so each XCD owns a contiguous 480-block chunk. Then the
    // +1281-vec shifted img window (next block's center) is same-XCD L2.
    const int bid = blockIdx.x;
    const int swz = (bid % NXCD) * CHUNK + bid / NXCD;
    const int base = swz * PER_BLOCK + threadIdx.x;

    const float DIST = 0.16901332f;   // exp(-16/9), spatial gaussian at (4,4)
    const float EPS  = 1e-12f;

    int     idx[UNROLL];
    floatx4 a[UNROLL], s[UNROLL], d[UNROLL];
    bool    sOK[UNROLL], dOK[UNROLL];

    // ---- load section: issue all 12 loads, branch-free (clamp + cndmask) ----
#pragma unroll
    for (int k = 0; k < UNROLL; ++k) {
        idx[k] = base + k * BLOCK;
        const int c4 = idx[k] % W4;
        const int r  = (idx[k] / W4) % H;
        sOK[k] = (r + PAD < H) & (c4 + 1 < W4);
        dOK[k] = (r >= PAD) & (c4 >= 1);
        const int sI = sOK[k] ? idx[k] + PAD * W4 + 1 : idx[k];
        const int dI = dOK[k] ? idx[k] - PAD * W4 - 1 : idx[k];
        a[k] = img[idx[k]];
        s[k] = img[sI];
        d[k] = disp[dI];
    }

    // Hard fence: compiler may not sink loads below / hoist compute above.
    // Forces all 12 global_load_dwordx4 in flight -> true MLP.
    __builtin_amdgcn_sched_barrier(0);

    // ---- compute + store section ----
#pragma unroll
    for (int k = 0; k < UNROLL; ++k) {
        if (!sOK[k]) s[k] = (floatx4)0.0f;
        if (!dOK[k]) d[k] = (floatx4)0.0f;

        floatx4 o;
#pragma unroll
        for (int j = 0; j < 4; ++j) {
            float diff = a[k][j] - s[k][j];
            float w    = DIST * __expf(diff * diff * -0.125f); // exp(-diff²/8)
            o[j] = __builtin_fmaf(d[k][j], w, EPS) * __builtin_amdgcn_rcpf(w + EPS);
        }
        out[idx[k]] = o;
    }
}

extern "C" void kernel_launch(void* const* d_in, const int* in_sizes, int n_in,
                              void* d_out, int out_size, void* d_ws, size_t ws_size,
                              hipStream_t stream) {
    const floatx4* img  = (const floatx4*)d_in[0];   // leftImage
    const floatx4* disp = (const floatx4*)d_in[1];   // estDisp
    floatx4* out = (floatx4*)d_out;

    bilateral_kernel<<<GRID, BLOCK, 0, stream>>>(img, disp, out);
}

// Round 5
// 32.286 us; speedup vs baseline: 1.2571x; 1.0134x over previous
//
#include <hip/hip_runtime.h>

typedef float floatx4 __attribute__((ext_vector_type(4)));

// Problem constants
constexpr int H    = 768;
constexpr int W4   = 1280 / 4;        // float4 per row = 320
constexpr int PAD  = 4;               // shift == one float4 (aligned!)
constexpr int NVEC = 16 * 768 * W4;   // 3,932,160 float4 elements
constexpr int UNROLL = 4;
constexpr int BLOCK  = 256;
constexpr int PER_BLOCK = BLOCK * UNROLL;      // 1024
constexpr int GRID = NVEC / PER_BLOCK;         // 3840 (exact)
constexpr int NXCD  = 8;
constexpr int CHUNK = GRID / NXCD;             // 480 (GRID % 8 == 0 -> bijective)

__global__ __launch_bounds__(256)
void bilateral_kernel(const floatx4* __restrict__ img,
                      const floatx4* __restrict__ disp,
                      floatx4* __restrict__ out)
{
    // XCD-aware swizzle (R3 WIN: FETCH 93->62 MB): each XCD owns a contiguous
    // 480-block chunk, so the +1281-vec shifted img window is same-XCD L2.
    const int bid = blockIdx.x;
    const int swz = (bid % NXCD) * CHUNK + bid / NXCD;
    const int base = swz * PER_BLOCK + threadIdx.x;

    const float DIST = 0.16901332f;   // exp(-16/9), spatial gaussian at (4,4)
    const float EPS  = 1e-12f;

    int     idx[UNROLL];
    floatx4 a[UNROLL], s[UNROLL], d[UNROLL];
    bool    sOK[UNROLL], dOK[UNROLL];

    // ---- load section: issue all 12 loads, branch-free (clamp + cndmask) ----
#pragma unroll
    for (int k = 0; k < UNROLL; ++k) {
        idx[k] = base + k * BLOCK;
        const int c4 = idx[k] % W4;
        const int r  = (idx[k] / W4) % H;
        sOK[k] = (r + PAD < H) & (c4 + 1 < W4);
        dOK[k] = (r >= PAD) & (c4 >= 1);
        const int sI = sOK[k] ? idx[k] + PAD * W4 + 1 : idx[k];
        const int dI = dOK[k] ? idx[k] - PAD * W4 - 1 : idx[k];
        a[k] = img[idx[k]];
        s[k] = img[sI];
        d[k] = disp[dI];
    }

    __builtin_amdgcn_sched_barrier(0);

    // ---- compute + store section ----
#pragma unroll
    for (int k = 0; k < UNROLL; ++k) {
        if (!sOK[k]) s[k] = (floatx4)0.0f;
        if (!dOK[k]) d[k] = (floatx4)0.0f;

        floatx4 o;
#pragma unroll
        for (int j = 0; j < 4; ++j) {
            float diff = a[k][j] - s[k][j];
            float w    = DIST * __expf(diff * diff * -0.125f); // exp(-diff²/8)
            o[j] = __builtin_fmaf(d[k][j], w, EPS) * __builtin_amdgcn_rcpf(w + EPS);
        }

        // Non-temporal store: output is never re-read; keep its 63 MB/replay
        // from write-allocating in L3 and evicting the L3-resident inputs.
        __builtin_nontemporal_store(o, &out[idx[k]]);
    }
}

extern "C" void kernel_launch(void* const* d_in, const int* in_sizes, int n_in,
                              void* d_out, int out_size, void* d_ws, size_t ws_size,
                              hipStream_t stream) {
    const floatx4* img  = (const floatx4*)d_in[0];   // leftImage
    const floatx4* disp = (const floatx4*)d_in[1];   // estDisp
    floatx4* out = (floatx4*)d_out;

    bilateral_kernel<<<GRID, BLOCK, 0, stream>>>(img, disp, out);
}